// Round 8
// baseline (3491.536 us; speedup 1.0000x reference)
//
#include <hip/hip_runtime.h>
#include <hip/hip_bf16.h>
#include <math.h>

#define Bn   32
#define Tn   256
#define DIN  768
#define DHn  512
#define DEn  25
#define Cn   9
#define K3   2304   // 3*DIN
#define H3   1536   // 3*DH
#define NCOL 3072   // 2*H3
#define MROW 8192   // B*T

typedef __attribute__((ext_vector_type(8))) short short8v;
typedef __attribute__((ext_vector_type(4))) float f32x4;

__device__ __forceinline__ unsigned short f2bf(float v) {
  __hip_bfloat16 h = __float2bfloat16(v);
  return __builtin_bit_cast(unsigned short, h);
}
__device__ __forceinline__ float bf2f(unsigned short u) {
  return __bfloat162float(__builtin_bit_cast(__hip_bfloat16, u));
}

// ================= preconversion kernels (bit-identical RNE split) =================
// Xs layout: [b][p(258)][768] bf16, p==0/257 are pad rows.
__global__ __launch_bounds__(256) void prep_x_kernel(
    const float* __restrict__ X, const float* __restrict__ pad,
    unsigned short* __restrict__ Xh, unsigned short* __restrict__ Xl)
{
  int e = blockIdx.x * 256 + threadIdx.x;       // one per 8-elem run
  if (e >= 32 * 258 * 96) return;
  int k8 = e % 96;
  int row = e / 96;                             // b*258 + p
  int p = row % 258, b = row / 258;
  int off = k8 * 8;
  const float* src = (p == 0 || p == 257) ? (pad + off)
                                          : (X + (size_t)(b * Tn + (p - 1)) * DIN + off);
  float4 v0 = *reinterpret_cast<const float4*>(src);
  float4 v1 = *reinterpret_cast<const float4*>(src + 4);
  float av[8] = {v0.x, v0.y, v0.z, v0.w, v1.x, v1.y, v1.z, v1.w};
  short8v h8, l8;
#pragma unroll
  for (int q = 0; q < 8; q++) {
    unsigned short h = f2bf(av[q]);
    h8[q] = (short)h;
    l8[q] = (short)f2bf(av[q] - bf2f(h));
  }
  *reinterpret_cast<short8v*>(Xh + (size_t)row * DIN + off) = h8;
  *reinterpret_cast<short8v*>(Xl + (size_t)row * DIN + off) = l8;
}

// Bs layout: [3072][2304] bf16; rows 0..1535 = Wih_f, 1536..3071 = Wih_b.
__global__ __launch_bounds__(256) void prep_wih_kernel(
    const float* __restrict__ Wf, const float* __restrict__ Wb,
    unsigned short* __restrict__ Bh, unsigned short* __restrict__ Bl)
{
  int e = blockIdx.x * 256 + threadIdx.x;
  if (e >= 3072 * 288) return;
  int k8 = e % 288;
  int rr = e / 288;
  int off = k8 * 8;
  const float* src = (rr < H3) ? (Wf + (size_t)rr * K3 + off)
                               : (Wb + (size_t)(rr - H3) * K3 + off);
  float4 v0 = *reinterpret_cast<const float4*>(src);
  float4 v1 = *reinterpret_cast<const float4*>(src + 4);
  float av[8] = {v0.x, v0.y, v0.z, v0.w, v1.x, v1.y, v1.z, v1.w};
  short8v h8, l8;
#pragma unroll
  for (int q = 0; q < 8; q++) {
    unsigned short h = f2bf(av[q]);
    h8[q] = (short)h;
    l8[q] = (short)f2bf(av[q] - bf2f(h));
  }
  *reinterpret_cast<short8v*>(Bh + (size_t)rr * K3 + off) = h8;
  *reinterpret_cast<short8v*>(Bl + (size_t)rr * K3 + off) = l8;
}

// ================= gi pre-GEMM (preconverted bf16 operands) =================
#define GBM 128
#define GBN 128
#define GBK 64
#define ASTR 72   // shorts per LDS row (64 + 8 pad)

__global__ __launch_bounds__(256) void gi_gemm_pc_kernel(
    const unsigned short* __restrict__ Xh, const unsigned short* __restrict__ Xl,
    const unsigned short* __restrict__ Bh, const unsigned short* __restrict__ Bl,
    const float* __restrict__ bf, const float* __restrict__ bb,
    float* __restrict__ gi)
{
  __shared__ __align__(16) unsigned short LAh[GBM * ASTR];
  __shared__ __align__(16) unsigned short LAl[GBM * ASTR];
  __shared__ __align__(16) unsigned short LBh[GBN * ASTR];
  __shared__ __align__(16) unsigned short LBl[GBN * ASTR];

  const int bnb = blockIdx.x, bmb = blockIdx.y;
  const int tid = threadIdx.x;
  const int m0 = bmb * GBM, n0 = bnb * GBN;
  const bool isF = (n0 < H3);
  const float* bias = isF ? bf : bb;
  const int nb0 = isF ? n0 : (n0 - H3);

  const int r = tid >> 1, half = tid & 1;
  const int m = m0 + r;
  const int ab = m >> 8, tpos = m & 255;

  const int wave = tid >> 6, lane = tid & 63;
  const int wr = wave >> 1, wc = wave & 1;
  const int lrow = lane & 15, lk = (lane >> 4) * 8;

  f32x4 acc[4][4];
#pragma unroll
  for (int i = 0; i < 4; i++)
#pragma unroll
    for (int j = 0; j < 4; j++) acc[i][j] = (f32x4){0.f, 0.f, 0.f, 0.f};

  for (int k0 = 0; k0 < K3; k0 += GBK) {
#pragma unroll
    for (int j2 = 0; j2 < 4; j2++) {
      const int kg = k0 + half * 32 + j2 * 8;
      const int seg = (kg >= DIN) + (kg >= 2 * DIN);
      const int off = kg - seg * DIN;
      const int p = tpos + seg;
      const size_t xi = (size_t)(ab * 258 + p) * DIN + off;
      const size_t bi = (size_t)(n0 + r) * K3 + kg;
      short8v a_h = *reinterpret_cast<const short8v*>(Xh + xi);
      short8v a_l = *reinterpret_cast<const short8v*>(Xl + xi);
      short8v b_h = *reinterpret_cast<const short8v*>(Bh + bi);
      short8v b_l = *reinterpret_cast<const short8v*>(Bl + bi);
      const int si = r * ASTR + half * 32 + j2 * 8;
      *reinterpret_cast<short8v*>(&LAh[si]) = a_h;
      *reinterpret_cast<short8v*>(&LAl[si]) = a_l;
      *reinterpret_cast<short8v*>(&LBh[si]) = b_h;
      *reinterpret_cast<short8v*>(&LBl[si]) = b_l;
    }
    __syncthreads();

#pragma unroll
    for (int ksub = 0; ksub < 2; ksub++) {
      short8v fah[4], fal[4], fbh[4], fbl[4];
#pragma unroll
      for (int i = 0; i < 4; i++) {
        const int ai = (wr * 64 + i * 16 + lrow) * ASTR + ksub * 32 + lk;
        const int bi2 = (wc * 64 + i * 16 + lrow) * ASTR + ksub * 32 + lk;
        fah[i] = *reinterpret_cast<const short8v*>(&LAh[ai]);
        fal[i] = *reinterpret_cast<const short8v*>(&LAl[ai]);
        fbh[i] = *reinterpret_cast<const short8v*>(&LBh[bi2]);
        fbl[i] = *reinterpret_cast<const short8v*>(&LBl[bi2]);
      }
#pragma unroll
      for (int mi = 0; mi < 4; mi++)
#pragma unroll
        for (int ni = 0; ni < 4; ni++) {
          acc[mi][ni] = __builtin_amdgcn_mfma_f32_16x16x32_bf16(fah[mi], fbh[ni], acc[mi][ni], 0, 0, 0);
          acc[mi][ni] = __builtin_amdgcn_mfma_f32_16x16x32_bf16(fah[mi], fbl[ni], acc[mi][ni], 0, 0, 0);
          acc[mi][ni] = __builtin_amdgcn_mfma_f32_16x16x32_bf16(fal[mi], fbh[ni], acc[mi][ni], 0, 0, 0);
        }
    }
    __syncthreads();
  }

#pragma unroll
  for (int ni = 0; ni < 4; ni++) {
    const int nl = wc * 64 + ni * 16 + (lane & 15);
    const float bvv = bias[nb0 + nl];
#pragma unroll
    for (int mi = 0; mi < 4; mi++) {
      const int mg = m0 + wr * 64 + mi * 16 + (lane >> 4) * 4;
#pragma unroll
      for (int reg = 0; reg < 4; reg++)
        gi[(size_t)(mg + reg) * NCOL + n0 + nl] = acc[mi][ni][reg] + bvv;
    }
  }
}

// ================= fallback gemm (in-kernel split; identical to R7) =================
__global__ __launch_bounds__(256) void gi_gemm_mfma_kernel(
    const float* __restrict__ X, const float* __restrict__ pad,
    const float* __restrict__ Wf, const float* __restrict__ Wb,
    const float* __restrict__ bf, const float* __restrict__ bb,
    float* __restrict__ gi)
{
  __shared__ __align__(16) unsigned short Ah[GBM * ASTR];
  __shared__ __align__(16) unsigned short Al[GBM * ASTR];
  __shared__ __align__(16) unsigned short Bh2[GBN * ASTR];
  __shared__ __align__(16) unsigned short Bl2[GBN * ASTR];

  const int bnb = blockIdx.x, bmb = blockIdx.y;
  const int tid = threadIdx.x;
  const int m0 = bmb * GBM, n0 = bnb * GBN;
  const bool isF = (n0 < H3);
  const float* Wmat = isF ? Wf : Wb;
  const float* bias = isF ? bf : bb;
  const int nb0 = isF ? n0 : (n0 - H3);

  const int r = tid >> 1, half = tid & 1;
  const int m = m0 + r;
  const int ab = m >> 8, tpos = m & 255;
  const float* wrowp = Wmat + (size_t)(nb0 + r) * K3;

  const int wave = tid >> 6, lane = tid & 63;
  const int wr = wave >> 1, wc = wave & 1;
  const int lrow = lane & 15, lk = (lane >> 4) * 8;

  f32x4 acc[4][4];
#pragma unroll
  for (int i = 0; i < 4; i++)
#pragma unroll
    for (int j = 0; j < 4; j++) acc[i][j] = (f32x4){0.f, 0.f, 0.f, 0.f};

  for (int k0 = 0; k0 < K3; k0 += GBK) {
#pragma unroll
    for (int j2 = 0; j2 < 4; j2++) {
      const int kg = k0 + half * 32 + j2 * 8;
      const int seg = (kg >= DIN) + (kg >= 2 * DIN);
      const int off = kg - seg * DIN;
      const int p = tpos + seg;
      const float* srcA = (p == 0 || p == Tn + 1)
                            ? (pad + off)
                            : (X + (size_t)(ab * Tn + (p - 1)) * DIN + off);
      float4 a0 = *reinterpret_cast<const float4*>(srcA);
      float4 a1 = *reinterpret_cast<const float4*>(srcA + 4);
      const float* srcB = wrowp + kg;
      float4 b0 = *reinterpret_cast<const float4*>(srcB);
      float4 b1 = *reinterpret_cast<const float4*>(srcB + 4);
      float av[8] = {a0.x, a0.y, a0.z, a0.w, a1.x, a1.y, a1.z, a1.w};
      float bv[8] = {b0.x, b0.y, b0.z, b0.w, b1.x, b1.y, b1.z, b1.w};
      short8v ah8, al8, bh8, bl8;
#pragma unroll
      for (int q = 0; q < 8; q++) {
        unsigned short h = f2bf(av[q]);
        ah8[q] = (short)h;
        al8[q] = (short)f2bf(av[q] - bf2f(h));
        unsigned short g = f2bf(bv[q]);
        bh8[q] = (short)g;
        bl8[q] = (short)f2bf(bv[q] - bf2f(g));
      }
      const int si = r * ASTR + half * 32 + j2 * 8;
      *reinterpret_cast<short8v*>(&Ah[si]) = ah8;
      *reinterpret_cast<short8v*>(&Al[si]) = al8;
      *reinterpret_cast<short8v*>(&Bh2[si]) = bh8;
      *reinterpret_cast<short8v*>(&Bl2[si]) = bl8;
    }
    __syncthreads();
#pragma unroll
    for (int ksub = 0; ksub < 2; ksub++) {
      short8v fah[4], fal[4], fbh[4], fbl[4];
#pragma unroll
      for (int i = 0; i < 4; i++) {
        const int ai = (wr * 64 + i * 16 + lrow) * ASTR + ksub * 32 + lk;
        const int bi = (wc * 64 + i * 16 + lrow) * ASTR + ksub * 32 + lk;
        fah[i] = *reinterpret_cast<const short8v*>(&Ah[ai]);
        fal[i] = *reinterpret_cast<const short8v*>(&Al[ai]);
        fbh[i] = *reinterpret_cast<const short8v*>(&Bh2[bi]);
        fbl[i] = *reinterpret_cast<const short8v*>(&Bl2[bi]);
      }
#pragma unroll
      for (int mi = 0; mi < 4; mi++)
#pragma unroll
        for (int ni = 0; ni < 4; ni++) {
          acc[mi][ni] = __builtin_amdgcn_mfma_f32_16x16x32_bf16(fah[mi], fbh[ni], acc[mi][ni], 0, 0, 0);
          acc[mi][ni] = __builtin_amdgcn_mfma_f32_16x16x32_bf16(fah[mi], fbl[ni], acc[mi][ni], 0, 0, 0);
          acc[mi][ni] = __builtin_amdgcn_mfma_f32_16x16x32_bf16(fal[mi], fbh[ni], acc[mi][ni], 0, 0, 0);
        }
    }
    __syncthreads();
  }
#pragma unroll
  for (int ni = 0; ni < 4; ni++) {
    const int nl = wc * 64 + ni * 16 + (lane & 15);
    const float bvv = bias[nb0 + nl];
#pragma unroll
    for (int mi = 0; mi < 4; mi++) {
      const int mg = m0 + wr * 64 + mi * 16 + (lane >> 4) * 4;
#pragma unroll
      for (int reg = 0; reg < 4; reg++)
        gi[(size_t)(mg + reg) * NCOL + n0 + nl] = acc[mi][ni][reg] + bvv;
    }
  }
}

// ================= prep: Wp + zero sync =================
__global__ __launch_bounds__(256) void prep_kernel(
    const float* __restrict__ Whh_f, const float* __restrict__ Whh_b,
    float4* __restrict__ Wp, unsigned* __restrict__ sync)
{
  int f = blockIdx.x * 256 + threadIdx.x;
  if (f < 8) sync[f * 32] = 0u;
  if (f >= 2 * 32 * 16 * 512) return;
  int k   = f & 511;
  int u   = (f >> 9) & 15;
  int slc = (f >> 13) & 31;
  int d   = f >> 18;
  const float* Wsrc = d ? Whh_b : Whh_f;
  int ug = slc * 16 + u;
  float4 v;
  v.x = Wsrc[(size_t)(0 * DHn + ug) * DHn + k];
  v.y = Wsrc[(size_t)(1 * DHn + ug) * DHn + k];
  v.z = Wsrc[(size_t)(2 * DHn + ug) * DHn + k];
  v.w = 0.f;
  Wp[f] = v;
}

// ---------------- etab[p][c] = emb[p] . Wc[c][1024:1049] ----------------
__global__ __launch_bounds__(128) void etab_kernel(
    const float* __restrict__ label_emb, const float* __restrict__ Wc,
    float* __restrict__ etab)
{
  int t = threadIdx.x;
  if (t >= 90) return;
  int p = t / Cn, c = t % Cn;
  float a = 0.f;
#pragma unroll
  for (int j = 0; j < DEn; j++)
    a = fmaf(label_emb[p * DEn + j], Wc[(size_t)c * 1049 + 1024 + j], a);
  etab[t] = a;
}

// ================= GRU recurrence: single-barrier, per-wave counter bumps =================
// counter target per step = 256 wave-bumps (32 WGs x 8 waves).
#define HSTRIDE 12

__global__ __launch_bounds__(512) void gru_rec6_kernel(
    const float* __restrict__ gi,
    const float4* __restrict__ Wp,
    const float* __restrict__ bhh_f, const float* __restrict__ bhh_b,
    unsigned* __restrict__ sync,
    float* __restrict__ hex,
    float* __restrict__ out)
{
  __shared__ __align__(16) float4 Wl[16 * 512];
  __shared__ __align__(16) float hl[512 * HSTRIDE];

  const int bid = blockIdx.x;
  const int xcd = bid & 7;
  const int d = xcd >> 2, g = xcd & 3;
  const int sl = bid >> 3;
  const int tid = threadIdx.x;
  const int ut = tid >> 5;
  const int kq2 = tid & 31;
  const int kq = kq2 & 15, bh = kq2 >> 4;
  const int grp = d * 4 + g;

  {
    const float4* src = Wp + (size_t)(d * 32 + sl) * 8192;
    for (int i = tid; i < 8192; i += 512) Wl[i] = src[i];
  }
  for (int i = tid; i < 512 * HSTRIDE; i += 512) hl[i] = 0.f;

  const float* bhh = d ? bhh_b : bhh_f;
  const int ug = sl * 16 + ut;
  const float br = bhh[ug], bz = bhh[DHn + ug], bn2 = bhh[2 * DHn + ug];
  const int blocal = ((kq & 1) << 1) | ((kq >> 1) & 1);
  const int b_l = bh * 4 + blocal;

  unsigned* cnt = sync + grp * 32;

  __syncthreads();   // Wl/hl init complete

  for (int s = 0; s < Tn; s++) {
    const int t = d ? (Tn - 1 - s) : s;

    // gi prefetch — independent of exchange, hides under poll
    float ir = 0.f, iz = 0.f, inn = 0.f;
    if (kq < 4) {
      const int bg = g * 8 + b_l;
      const float* gp = gi + (size_t)(bg * Tn + t) * NCOL + d * H3 + ug;
      ir = gp[0]; iz = gp[DHn]; inn = gp[2 * DHn];
    }

    if (s > 0) {
      // per-wave poll: all 64 lanes load same address (one request)
      const unsigned tgt = 256u * (unsigned)s;
      while (__hip_atomic_load(cnt, __ATOMIC_RELAXED, __HIP_MEMORY_SCOPE_SYSTEM) < tgt)
        __builtin_amdgcn_s_sleep(1);
      asm volatile("" ::: "memory");
      // readback h(s-1): 4 u64 system loads per thread -> ds_write
      const uint64_t* src = reinterpret_cast<const uint64_t*>(
          hex + (size_t)(((s - 1) & 1) * 8 + grp) * (512 * 8));
#pragma unroll
      for (int j = 0; j < 4; j++) {
        int idx = tid + 512 * j;
        uint64_t v = __hip_atomic_load(src + idx,
                                       __ATOMIC_RELAXED, __HIP_MEMORY_SCOPE_SYSTEM);
        int fd = 2 * idx;
        int u = fd >> 3, b = fd & 7;
        *reinterpret_cast<uint64_t*>(&hl[u * HSTRIDE + b]) = v;
      }
    }
    __syncthreads();   // the ONE barrier: all hl writes visible to all waves

    float acc[3][4];
#pragma unroll
    for (int gg = 0; gg < 3; gg++)
#pragma unroll
      for (int bb = 0; bb < 4; bb++) acc[gg][bb] = 0.f;

#pragma unroll 4
    for (int i = 0; i < 32; i++) {
      int k = i * 16 + kq;
      float4 wv = Wl[ut * 512 + k];
      float4 ha = *reinterpret_cast<const float4*>(&hl[k * HSTRIDE + bh * 4]);
      acc[0][0] = fmaf(wv.x, ha.x, acc[0][0]); acc[0][1] = fmaf(wv.x, ha.y, acc[0][1]);
      acc[0][2] = fmaf(wv.x, ha.z, acc[0][2]); acc[0][3] = fmaf(wv.x, ha.w, acc[0][3]);
      acc[1][0] = fmaf(wv.y, ha.x, acc[1][0]); acc[1][1] = fmaf(wv.y, ha.y, acc[1][1]);
      acc[1][2] = fmaf(wv.y, ha.z, acc[1][2]); acc[1][3] = fmaf(wv.y, ha.w, acc[1][3]);
      acc[2][0] = fmaf(wv.z, ha.x, acc[2][0]); acc[2][1] = fmaf(wv.z, ha.y, acc[2][1]);
      acc[2][2] = fmaf(wv.z, ha.z, acc[2][2]); acc[2][3] = fmaf(wv.z, ha.w, acc[2][3]);
    }

#pragma unroll
    for (int gg = 0; gg < 3; gg++)
#pragma unroll
      for (int bb = 0; bb < 4; bb++)
        acc[gg][bb] += __shfl_xor(acc[gg][bb], 8);

    float a2[3][2];
#pragma unroll
    for (int gg = 0; gg < 3; gg++)
#pragma unroll
      for (int j = 0; j < 2; j++) {
        float keep = (kq & 1) ? acc[gg][2 + j] : acc[gg][j];
        float send = (kq & 1) ? acc[gg][j] : acc[gg][2 + j];
        a2[gg][j] = keep + __shfl_xor(send, 1);
      }
    float a1[3];
#pragma unroll
    for (int gg = 0; gg < 3; gg++) {
      float keep = (kq & 2) ? a2[gg][1] : a2[gg][0];
      float send = (kq & 2) ? a2[gg][0] : a2[gg][1];
      a1[gg] = keep + __shfl_xor(send, 2);
    }
#pragma unroll
    for (int gg = 0; gg < 3; gg++)
      a1[gg] += __shfl_xor(a1[gg], 4);

    if (kq < 4) {
      const float r = 1.f / (1.f + expf(-(ir + a1[0] + br)));
      const float z = 1.f / (1.f + expf(-(iz + a1[1] + bz)));
      const float n = tanhf(inn + r * (a1[2] + bn2));
      const float hold = hl[ug * HSTRIDE + b_l];
      const float hnew = (1.f - z) * n + z * hold;
      __hip_atomic_store(&hex[((size_t)(s & 1) * 8 + grp) * (512 * 8) + ug * 8 + b_l],
                         hnew, __ATOMIC_RELAXED, __HIP_MEMORY_SCOPE_SYSTEM);
      out[(size_t)((g * 8 + b_l) * Tn + t) * 1024 + d * DHn + ug] = hnew;
    }
    // wave-level drain: hex stores MALL-complete before this wave's bump
    asm volatile("s_waitcnt vmcnt(0)" ::: "memory");
    if (s < Tn - 1 && (tid & 63) == 0)
      __hip_atomic_fetch_add(cnt, 1u, __ATOMIC_RELAXED, __HIP_MEMORY_SCOPE_SYSTEM);
  }
}

// ---------------- lh[b*T+t][c] = h . Wc[c][:1024] + bc[c] ----------------
__global__ __launch_bounds__(256) void lh_kernel(
    const float* __restrict__ out_h, const float* __restrict__ Wc,
    const float* __restrict__ bc, float* __restrict__ lh)
{
  const int tid = threadIdx.x;
  const int wave = tid >> 6, lane = tid & 63;
#pragma unroll 1
  for (int it = 0; it < 16; it++) {
    const int row = blockIdx.x * 64 + wave * 16 + it;
    const float* hp = out_h + (size_t)row * 1024 + lane * 4;
    float4 hv[4];
#pragma unroll
    for (int j = 0; j < 4; j++) hv[j] = *reinterpret_cast<const float4*>(hp + 256 * j);
    float acc[Cn];
#pragma unroll
    for (int c = 0; c < Cn; c++) {
      const float* wp = Wc + (size_t)c * 1049 + lane * 4;
      float a = 0.f;
#pragma unroll
      for (int j = 0; j < 4; j++) {
        float4 wv = *reinterpret_cast<const float4*>(wp + 256 * j);
        a = fmaf(hv[j].x, wv.x, a); a = fmaf(hv[j].y, wv.y, a);
        a = fmaf(hv[j].z, wv.z, a); a = fmaf(hv[j].w, wv.w, a);
      }
      acc[c] = a;
    }
#pragma unroll
    for (int off = 32; off; off >>= 1)
#pragma unroll
      for (int c = 0; c < Cn; c++) acc[c] += __shfl_xor(acc[c], off);
    if (lane < Cn) lh[(size_t)row * 12 + lane] = acc[lane] + bc[lane];
  }
}

// ---------------- chain: per-batch argmax feedback ----------------
__global__ __launch_bounds__(64) void chain_kernel(
    const float* __restrict__ lh, const float* __restrict__ etab,
    float* __restrict__ outc)
{
  __shared__ float et[90];
  const int tid = threadIdx.x;
  if (tid < 90) et[tid] = etab[tid];
  __syncthreads();
  if (tid >= Bn) return;
  const int b = tid;
  const float* base = lh + (size_t)b * Tn * 12;
  float4 A0 = *reinterpret_cast<const float4*>(base);
  float4 A1 = *reinterpret_cast<const float4*>(base + 4);
  float c8 = base[8];
  int prev = Cn;
  for (int t = 0; t < Tn; t++) {
    float4 N0 = {0,0,0,0}, N1 = {0,0,0,0}; float nc8 = 0.f;
    if (t < Tn - 1) {
      const float* nb = base + (size_t)(t + 1) * 12;
      N0 = *reinterpret_cast<const float4*>(nb);
      N1 = *reinterpret_cast<const float4*>(nb + 4);
      nc8 = nb[8];
    }
    float lg[Cn] = {A0.x, A0.y, A0.z, A0.w, A1.x, A1.y, A1.z, A1.w, c8};
    const float* ep = &et[prev * Cn];
#pragma unroll
    for (int c = 0; c < Cn; c++) lg[c] += ep[c];
    float mx = lg[0]; int idx = 0;
#pragma unroll
    for (int c = 1; c < Cn; c++) if (lg[c] > mx) { mx = lg[c]; idx = c; }
    float e[Cn]; float sum = 0.f;
#pragma unroll
    for (int c = 0; c < Cn; c++) { e[c] = expf(lg[c] - mx); sum += e[c]; }
    const float inv = 1.f / sum;
    float* op = outc + ((size_t)b * Tn + t) * Cn;
#pragma unroll
    for (int c = 0; c < Cn; c++) op[c] = e[c] * inv;
    prev = idx;
    A0 = N0; A1 = N1; c8 = nc8;
  }
}

extern "C" void kernel_launch(void* const* d_in, const int* in_sizes, int n_in,
                              void* d_out, int out_size, void* d_ws, size_t ws_size,
                              hipStream_t stream) {
  const float* X      = (const float*)d_in[0];
  const float* pad    = (const float*)d_in[1];
  const float* lemb   = (const float*)d_in[2];
  const float* Wih_f  = (const float*)d_in[3];
  const float* Whh_f  = (const float*)d_in[4];
  const float* bih_f  = (const float*)d_in[5];
  const float* bhh_f  = (const float*)d_in[6];
  const float* Wih_b  = (const float*)d_in[7];
  const float* Whh_b  = (const float*)d_in[8];
  const float* bih_b  = (const float*)d_in[9];
  const float* bhh_b  = (const float*)d_in[10];
  const float* Wc     = (const float*)d_in[11];
  const float* bc     = (const float*)d_in[12];
  float* out = (float*)d_out;

  char* ws = (char*)d_ws;
  float*    gi   = (float*)ws;                                          // 100,663,296
  float4*   Wp   = (float4*)(ws + 100663296);                           // 8,388,608
  unsigned* sync = (unsigned*)(ws + 109051904);                         // 1,024
  float*    hex  = (float*)(ws + 109052928);                            // 262,144
  unsigned short* Xh = (unsigned short*)(ws + 109315072);               // 12,681,216
  unsigned short* Xl = (unsigned short*)(ws + 121996288);               // 12,681,216
  unsigned short* Bh = (unsigned short*)(ws + 134677504);               // 14,155,776
  unsigned short* Bl = (unsigned short*)(ws + 148833280);               // 14,155,776 -> 162,989,056
  float*    lh   = (float*)ws;                                          // post-gru alias
  float*    etab = (float*)(ws + 524288);                               // post-gru alias

  const bool preconv = (ws_size >= (size_t)162989056ULL);

  prep_kernel<<<dim3(2048), dim3(256), 0, stream>>>(Whh_f, Whh_b, Wp, sync);
  if (preconv) {
    prep_x_kernel<<<dim3((32 * 258 * 96 + 255) / 256), dim3(256), 0, stream>>>(X, pad, Xh, Xl);
    prep_wih_kernel<<<dim3((3072 * 288 + 255) / 256), dim3(256), 0, stream>>>(Wih_f, Wih_b, Bh, Bl);
    gi_gemm_pc_kernel<<<dim3(NCOL / GBN, MROW / GBM), dim3(256), 0, stream>>>(
        Xh, Xl, Bh, Bl, bih_f, bih_b, gi);
  } else {
    gi_gemm_mfma_kernel<<<dim3(NCOL / GBN, MROW / GBM), dim3(256), 0, stream>>>(
        X, pad, Wih_f, Wih_b, bih_f, bih_b, gi);
  }
  gru_rec6_kernel<<<dim3(256), dim3(512), 0, stream>>>(gi, Wp, bhh_f, bhh_b, sync, hex, out);
  etab_kernel<<<dim3(1), dim3(128), 0, stream>>>(lemb, Wc, etab);
  lh_kernel<<<dim3(128), dim3(256), 0, stream>>>(out, Wc, bc, lh);
  chain_kernel<<<dim3(1), dim3(64), 0, stream>>>(lh, etab, out + (size_t)MROW * 1024);
}

// Round 9
// 1730.809 us; speedup vs baseline: 2.0173x; 2.0173x over previous
//
#include <hip/hip_runtime.h>
#include <hip/hip_bf16.h>
#include <math.h>

#define Bn   32
#define Tn   256
#define DIN  768
#define DHn  512
#define DEn  25
#define Cn   9
#define K3   2304   // 3*DIN
#define H3   1536   // 3*DH
#define NCOL 3072   // 2*H3
#define MROW 8192   // B*T

typedef __attribute__((ext_vector_type(8))) short short8v;
typedef __attribute__((ext_vector_type(4))) float f32x4;

__device__ __forceinline__ unsigned short f2bf(float v) {
  __hip_bfloat16 h = __float2bfloat16(v);
  return __builtin_bit_cast(unsigned short, h);
}
__device__ __forceinline__ float bf2f(unsigned short u) {
  return __bfloat162float(__builtin_bit_cast(__hip_bfloat16, u));
}

// ================= preconversion kernels (bit-identical RNE split) =================
__global__ __launch_bounds__(256) void prep_x_kernel(
    const float* __restrict__ X, const float* __restrict__ pad,
    unsigned short* __restrict__ Xh, unsigned short* __restrict__ Xl)
{
  int e = blockIdx.x * 256 + threadIdx.x;       // one per 8-elem run
  if (e >= 32 * 258 * 96) return;
  int k8 = e % 96;
  int row = e / 96;                             // b*258 + p
  int p = row % 258, b = row / 258;
  int off = k8 * 8;
  const float* src = (p == 0 || p == 257) ? (pad + off)
                                          : (X + (size_t)(b * Tn + (p - 1)) * DIN + off);
  float4 v0 = *reinterpret_cast<const float4*>(src);
  float4 v1 = *reinterpret_cast<const float4*>(src + 4);
  float av[8] = {v0.x, v0.y, v0.z, v0.w, v1.x, v1.y, v1.z, v1.w};
  short8v h8, l8;
#pragma unroll
  for (int q = 0; q < 8; q++) {
    unsigned short h = f2bf(av[q]);
    h8[q] = (short)h;
    l8[q] = (short)f2bf(av[q] - bf2f(h));
  }
  *reinterpret_cast<short8v*>(Xh + (size_t)row * DIN + off) = h8;
  *reinterpret_cast<short8v*>(Xl + (size_t)row * DIN + off) = l8;
}

__global__ __launch_bounds__(256) void prep_wih_kernel(
    const float* __restrict__ Wf, const float* __restrict__ Wb,
    unsigned short* __restrict__ Bh, unsigned short* __restrict__ Bl)
{
  int e = blockIdx.x * 256 + threadIdx.x;
  if (e >= 3072 * 288) return;
  int k8 = e % 288;
  int rr = e / 288;
  int off = k8 * 8;
  const float* src = (rr < H3) ? (Wf + (size_t)rr * K3 + off)
                               : (Wb + (size_t)(rr - H3) * K3 + off);
  float4 v0 = *reinterpret_cast<const float4*>(src);
  float4 v1 = *reinterpret_cast<const float4*>(src + 4);
  float av[8] = {v0.x, v0.y, v0.z, v0.w, v1.x, v1.y, v1.z, v1.w};
  short8v h8, l8;
#pragma unroll
  for (int q = 0; q < 8; q++) {
    unsigned short h = f2bf(av[q]);
    h8[q] = (short)h;
    l8[q] = (short)f2bf(av[q] - bf2f(h));
  }
  *reinterpret_cast<short8v*>(Bh + (size_t)rr * K3 + off) = h8;
  *reinterpret_cast<short8v*>(Bl + (size_t)rr * K3 + off) = l8;
}

// ================= gi pre-GEMM (preconverted bf16 operands) =================
#define GBM 128
#define GBN 128
#define GBK 64
#define ASTR 72   // shorts per LDS row (64 + 8 pad)

__global__ __launch_bounds__(256) void gi_gemm_pc_kernel(
    const unsigned short* __restrict__ Xh, const unsigned short* __restrict__ Xl,
    const unsigned short* __restrict__ Bh, const unsigned short* __restrict__ Bl,
    const float* __restrict__ bf, const float* __restrict__ bb,
    float* __restrict__ gi)
{
  __shared__ __align__(16) unsigned short LAh[GBM * ASTR];
  __shared__ __align__(16) unsigned short LAl[GBM * ASTR];
  __shared__ __align__(16) unsigned short LBh[GBN * ASTR];
  __shared__ __align__(16) unsigned short LBl[GBN * ASTR];

  const int bnb = blockIdx.x, bmb = blockIdx.y;
  const int tid = threadIdx.x;
  const int m0 = bmb * GBM, n0 = bnb * GBN;
  const bool isF = (n0 < H3);
  const float* bias = isF ? bf : bb;
  const int nb0 = isF ? n0 : (n0 - H3);

  const int r = tid >> 1, half = tid & 1;
  const int m = m0 + r;
  const int ab = m >> 8, tpos = m & 255;

  const int wave = tid >> 6, lane = tid & 63;
  const int wr = wave >> 1, wc = wave & 1;
  const int lrow = lane & 15, lk = (lane >> 4) * 8;

  f32x4 acc[4][4];
#pragma unroll
  for (int i = 0; i < 4; i++)
#pragma unroll
    for (int j = 0; j < 4; j++) acc[i][j] = (f32x4){0.f, 0.f, 0.f, 0.f};

  for (int k0 = 0; k0 < K3; k0 += GBK) {
#pragma unroll
    for (int j2 = 0; j2 < 4; j2++) {
      const int kg = k0 + half * 32 + j2 * 8;
      const int seg = (kg >= DIN) + (kg >= 2 * DIN);
      const int off = kg - seg * DIN;
      const int p = tpos + seg;
      const size_t xi = (size_t)(ab * 258 + p) * DIN + off;
      const size_t bi = (size_t)(n0 + r) * K3 + kg;
      short8v a_h = *reinterpret_cast<const short8v*>(Xh + xi);
      short8v a_l = *reinterpret_cast<const short8v*>(Xl + xi);
      short8v b_h = *reinterpret_cast<const short8v*>(Bh + bi);
      short8v b_l = *reinterpret_cast<const short8v*>(Bl + bi);
      const int si = r * ASTR + half * 32 + j2 * 8;
      *reinterpret_cast<short8v*>(&LAh[si]) = a_h;
      *reinterpret_cast<short8v*>(&LAl[si]) = a_l;
      *reinterpret_cast<short8v*>(&LBh[si]) = b_h;
      *reinterpret_cast<short8v*>(&LBl[si]) = b_l;
    }
    __syncthreads();

#pragma unroll
    for (int ksub = 0; ksub < 2; ksub++) {
      short8v fah[4], fal[4], fbh[4], fbl[4];
#pragma unroll
      for (int i = 0; i < 4; i++) {
        const int ai = (wr * 64 + i * 16 + lrow) * ASTR + ksub * 32 + lk;
        const int bi2 = (wc * 64 + i * 16 + lrow) * ASTR + ksub * 32 + lk;
        fah[i] = *reinterpret_cast<const short8v*>(&LAh[ai]);
        fal[i] = *reinterpret_cast<const short8v*>(&LAl[ai]);
        fbh[i] = *reinterpret_cast<const short8v*>(&LBh[bi2]);
        fbl[i] = *reinterpret_cast<const short8v*>(&LBl[bi2]);
      }
#pragma unroll
      for (int mi = 0; mi < 4; mi++)
#pragma unroll
        for (int ni = 0; ni < 4; ni++) {
          acc[mi][ni] = __builtin_amdgcn_mfma_f32_16x16x32_bf16(fah[mi], fbh[ni], acc[mi][ni], 0, 0, 0);
          acc[mi][ni] = __builtin_amdgcn_mfma_f32_16x16x32_bf16(fah[mi], fbl[ni], acc[mi][ni], 0, 0, 0);
          acc[mi][ni] = __builtin_amdgcn_mfma_f32_16x16x32_bf16(fal[mi], fbh[ni], acc[mi][ni], 0, 0, 0);
        }
    }
    __syncthreads();
  }

#pragma unroll
  for (int ni = 0; ni < 4; ni++) {
    const int nl = wc * 64 + ni * 16 + (lane & 15);
    const float bvv = bias[nb0 + nl];
#pragma unroll
    for (int mi = 0; mi < 4; mi++) {
      const int mg = m0 + wr * 64 + mi * 16 + (lane >> 4) * 4;
#pragma unroll
      for (int reg = 0; reg < 4; reg++)
        gi[(size_t)(mg + reg) * NCOL + n0 + nl] = acc[mi][ni][reg] + bvv;
    }
  }
}

// ================= fallback gemm (in-kernel split; identical math) =================
__global__ __launch_bounds__(256) void gi_gemm_mfma_kernel(
    const float* __restrict__ X, const float* __restrict__ pad,
    const float* __restrict__ Wf, const float* __restrict__ Wb,
    const float* __restrict__ bf, const float* __restrict__ bb,
    float* __restrict__ gi)
{
  __shared__ __align__(16) unsigned short Ah[GBM * ASTR];
  __shared__ __align__(16) unsigned short Al[GBM * ASTR];
  __shared__ __align__(16) unsigned short Bh2[GBN * ASTR];
  __shared__ __align__(16) unsigned short Bl2[GBN * ASTR];

  const int bnb = blockIdx.x, bmb = blockIdx.y;
  const int tid = threadIdx.x;
  const int m0 = bmb * GBM, n0 = bnb * GBN;
  const bool isF = (n0 < H3);
  const float* Wmat = isF ? Wf : Wb;
  const float* bias = isF ? bf : bb;
  const int nb0 = isF ? n0 : (n0 - H3);

  const int r = tid >> 1, half = tid & 1;
  const int m = m0 + r;
  const int ab = m >> 8, tpos = m & 255;
  const float* wrowp = Wmat + (size_t)(nb0 + r) * K3;

  const int wave = tid >> 6, lane = tid & 63;
  const int wr = wave >> 1, wc = wave & 1;
  const int lrow = lane & 15, lk = (lane >> 4) * 8;

  f32x4 acc[4][4];
#pragma unroll
  for (int i = 0; i < 4; i++)
#pragma unroll
    for (int j = 0; j < 4; j++) acc[i][j] = (f32x4){0.f, 0.f, 0.f, 0.f};

  for (int k0 = 0; k0 < K3; k0 += GBK) {
#pragma unroll
    for (int j2 = 0; j2 < 4; j2++) {
      const int kg = k0 + half * 32 + j2 * 8;
      const int seg = (kg >= DIN) + (kg >= 2 * DIN);
      const int off = kg - seg * DIN;
      const int p = tpos + seg;
      const float* srcA = (p == 0 || p == Tn + 1)
                            ? (pad + off)
                            : (X + (size_t)(ab * Tn + (p - 1)) * DIN + off);
      float4 a0 = *reinterpret_cast<const float4*>(srcA);
      float4 a1 = *reinterpret_cast<const float4*>(srcA + 4);
      const float* srcB = wrowp + kg;
      float4 b0 = *reinterpret_cast<const float4*>(srcB);
      float4 b1 = *reinterpret_cast<const float4*>(srcB + 4);
      float av[8] = {a0.x, a0.y, a0.z, a0.w, a1.x, a1.y, a1.z, a1.w};
      float bv[8] = {b0.x, b0.y, b0.z, b0.w, b1.x, b1.y, b1.z, b1.w};
      short8v ah8, al8, bh8, bl8;
#pragma unroll
      for (int q = 0; q < 8; q++) {
        unsigned short h = f2bf(av[q]);
        ah8[q] = (short)h;
        al8[q] = (short)f2bf(av[q] - bf2f(h));
        unsigned short g = f2bf(bv[q]);
        bh8[q] = (short)g;
        bl8[q] = (short)f2bf(bv[q] - bf2f(g));
      }
      const int si = r * ASTR + half * 32 + j2 * 8;
      *reinterpret_cast<short8v*>(&Ah[si]) = ah8;
      *reinterpret_cast<short8v*>(&Al[si]) = al8;
      *reinterpret_cast<short8v*>(&Bh2[si]) = bh8;
      *reinterpret_cast<short8v*>(&Bl2[si]) = bl8;
    }
    __syncthreads();
#pragma unroll
    for (int ksub = 0; ksub < 2; ksub++) {
      short8v fah[4], fal[4], fbh[4], fbl[4];
#pragma unroll
      for (int i = 0; i < 4; i++) {
        const int ai = (wr * 64 + i * 16 + lrow) * ASTR + ksub * 32 + lk;
        const int bi = (wc * 64 + i * 16 + lrow) * ASTR + ksub * 32 + lk;
        fah[i] = *reinterpret_cast<const short8v*>(&Ah[ai]);
        fal[i] = *reinterpret_cast<const short8v*>(&Al[ai]);
        fbh[i] = *reinterpret_cast<const short8v*>(&Bh2[bi]);
        fbl[i] = *reinterpret_cast<const short8v*>(&Bl2[bi]);
      }
#pragma unroll
      for (int mi = 0; mi < 4; mi++)
#pragma unroll
        for (int ni = 0; ni < 4; ni++) {
          acc[mi][ni] = __builtin_amdgcn_mfma_f32_16x16x32_bf16(fah[mi], fbh[ni], acc[mi][ni], 0, 0, 0);
          acc[mi][ni] = __builtin_amdgcn_mfma_f32_16x16x32_bf16(fah[mi], fbl[ni], acc[mi][ni], 0, 0, 0);
          acc[mi][ni] = __builtin_amdgcn_mfma_f32_16x16x32_bf16(fal[mi], fbh[ni], acc[mi][ni], 0, 0, 0);
        }
    }
    __syncthreads();
  }
#pragma unroll
  for (int ni = 0; ni < 4; ni++) {
    const int nl = wc * 64 + ni * 16 + (lane & 15);
    const float bvv = bias[nb0 + nl];
#pragma unroll
    for (int mi = 0; mi < 4; mi++) {
      const int mg = m0 + wr * 64 + mi * 16 + (lane >> 4) * 4;
#pragma unroll
      for (int reg = 0; reg < 4; reg++)
        gi[(size_t)(mg + reg) * NCOL + n0 + nl] = acc[mi][ni][reg] + bvv;
    }
  }
}

// ================= prep: Wp + zero sync =================
__global__ __launch_bounds__(256) void prep_kernel(
    const float* __restrict__ Whh_f, const float* __restrict__ Whh_b,
    float4* __restrict__ Wp, unsigned* __restrict__ sync)
{
  int f = blockIdx.x * 256 + threadIdx.x;
  if (f < 8) sync[f * 32] = 0u;
  if (f >= 2 * 32 * 16 * 512) return;
  int k   = f & 511;
  int u   = (f >> 9) & 15;
  int slc = (f >> 13) & 31;
  int d   = f >> 18;
  const float* Wsrc = d ? Whh_b : Whh_f;
  int ug = slc * 16 + u;
  float4 v;
  v.x = Wsrc[(size_t)(0 * DHn + ug) * DHn + k];
  v.y = Wsrc[(size_t)(1 * DHn + ug) * DHn + k];
  v.z = Wsrc[(size_t)(2 * DHn + ug) * DHn + k];
  v.w = 0.f;
  Wp[f] = v;
}

// ---------------- etab[p][c] = emb[p] . Wc[c][1024:1049] ----------------
__global__ __launch_bounds__(128) void etab_kernel(
    const float* __restrict__ label_emb, const float* __restrict__ Wc,
    float* __restrict__ etab)
{
  int t = threadIdx.x;
  if (t >= 90) return;
  int p = t / Cn, c = t % Cn;
  float a = 0.f;
#pragma unroll
  for (int j = 0; j < DEn; j++)
    a = fmaf(label_emb[p * DEn + j], Wc[(size_t)c * 1049 + 1024 + j], a);
  etab[t] = a;
}

// ================= GRU recurrence (rec5: proven R7 sync structure) =================
// 512 threads: (ut 0..15, kq 0..15, bh 0..1); tid0 poll + 3 barriers/step;
// one counter bump per WG per step. Bit-identical math (chains + 8,1,2,4 tree).
#define HSTRIDE 12

__global__ __launch_bounds__(512) void gru_rec5_kernel(
    const float* __restrict__ gi,
    const float4* __restrict__ Wp,
    const float* __restrict__ bhh_f, const float* __restrict__ bhh_b,
    unsigned* __restrict__ sync,
    float* __restrict__ hex,
    float* __restrict__ out)
{
  __shared__ __align__(16) float4 Wl[16 * 512];
  __shared__ __align__(16) float hl[512 * HSTRIDE];

  const int bid = blockIdx.x;
  const int xcd = bid & 7;
  const int d = xcd >> 2, g = xcd & 3;
  const int sl = bid >> 3;
  const int tid = threadIdx.x;
  const int ut = tid >> 5;
  const int kq2 = tid & 31;
  const int kq = kq2 & 15, bh = kq2 >> 4;
  const int grp = d * 4 + g;

  {
    const float4* src = Wp + (size_t)(d * 32 + sl) * 8192;
    for (int i = tid; i < 8192; i += 512) Wl[i] = src[i];
  }
  for (int i = tid; i < 512 * HSTRIDE; i += 512) hl[i] = 0.f;

  const float* bhh = d ? bhh_b : bhh_f;
  const int ug = sl * 16 + ut;
  const float br = bhh[ug], bz = bhh[DHn + ug], bn2 = bhh[2 * DHn + ug];
  const int blocal = ((kq & 1) << 1) | ((kq >> 1) & 1);
  const int b_l = bh * 4 + blocal;

  unsigned* cnt = sync + grp * 32;

  __syncthreads();

  for (int s = 0; s < Tn; s++) {
    const int t = d ? (Tn - 1 - s) : s;

    // gi prefetch (independent of exchange; hides MALL/HBM latency under poll)
    float ir = 0.f, iz = 0.f, inn = 0.f;
    if (kq < 4) {
      const int bg = g * 8 + b_l;
      const float* gp = gi + (size_t)(bg * Tn + t) * NCOL + d * H3 + ug;
      ir = gp[0]; iz = gp[DHn]; inn = gp[2 * DHn];
    }

    if (s > 0) {
      if (tid == 0) {
        const unsigned tgt = 32u * (unsigned)s;
        while (__hip_atomic_load(cnt, __ATOMIC_RELAXED, __HIP_MEMORY_SCOPE_SYSTEM) < tgt)
          __builtin_amdgcn_s_sleep(1);
      }
      __syncthreads();
      asm volatile("" ::: "memory");
      // readback h(s-1): 2048 u64 system loads, 4 per thread
      const uint64_t* src = reinterpret_cast<const uint64_t*>(
          hex + (size_t)(((s - 1) & 1) * 8 + grp) * (512 * 8));
#pragma unroll
      for (int j = 0; j < 4; j++) {
        int idx = tid + 512 * j;
        uint64_t v = __hip_atomic_load(src + idx,
                                       __ATOMIC_RELAXED, __HIP_MEMORY_SCOPE_SYSTEM);
        int fd = 2 * idx;
        int u = fd >> 3, b = fd & 7;
        *reinterpret_cast<uint64_t*>(&hl[u * HSTRIDE + b]) = v;
      }
      __syncthreads();
    }

    float acc[3][4];
#pragma unroll
    for (int gg = 0; gg < 3; gg++)
#pragma unroll
      for (int bb = 0; bb < 4; bb++) acc[gg][bb] = 0.f;

#pragma unroll 4
    for (int i = 0; i < 32; i++) {
      int k = i * 16 + kq;
      float4 wv = Wl[ut * 512 + k];
      float4 ha = *reinterpret_cast<const float4*>(&hl[k * HSTRIDE + bh * 4]);
      acc[0][0] = fmaf(wv.x, ha.x, acc[0][0]); acc[0][1] = fmaf(wv.x, ha.y, acc[0][1]);
      acc[0][2] = fmaf(wv.x, ha.z, acc[0][2]); acc[0][3] = fmaf(wv.x, ha.w, acc[0][3]);
      acc[1][0] = fmaf(wv.y, ha.x, acc[1][0]); acc[1][1] = fmaf(wv.y, ha.y, acc[1][1]);
      acc[1][2] = fmaf(wv.y, ha.z, acc[1][2]); acc[1][3] = fmaf(wv.y, ha.w, acc[1][3]);
      acc[2][0] = fmaf(wv.z, ha.x, acc[2][0]); acc[2][1] = fmaf(wv.z, ha.y, acc[2][1]);
      acc[2][2] = fmaf(wv.z, ha.z, acc[2][2]); acc[2][3] = fmaf(wv.z, ha.w, acc[2][3]);
    }

#pragma unroll
    for (int gg = 0; gg < 3; gg++)
#pragma unroll
      for (int bb = 0; bb < 4; bb++)
        acc[gg][bb] += __shfl_xor(acc[gg][bb], 8);

    float a2[3][2];
#pragma unroll
    for (int gg = 0; gg < 3; gg++)
#pragma unroll
      for (int j = 0; j < 2; j++) {
        float keep = (kq & 1) ? acc[gg][2 + j] : acc[gg][j];
        float send = (kq & 1) ? acc[gg][j] : acc[gg][2 + j];
        a2[gg][j] = keep + __shfl_xor(send, 1);
      }
    float a1[3];
#pragma unroll
    for (int gg = 0; gg < 3; gg++) {
      float keep = (kq & 2) ? a2[gg][1] : a2[gg][0];
      float send = (kq & 2) ? a2[gg][0] : a2[gg][1];
      a1[gg] = keep + __shfl_xor(send, 2);
    }
#pragma unroll
    for (int gg = 0; gg < 3; gg++)
      a1[gg] += __shfl_xor(a1[gg], 4);

    float hnew = 0.f;
    if (kq < 4) {
      const float r = 1.f / (1.f + expf(-(ir + a1[0] + br)));
      const float z = 1.f / (1.f + expf(-(iz + a1[1] + bz)));
      const float n = tanhf(inn + r * (a1[2] + bn2));
      const float hold = hl[ug * HSTRIDE + b_l];
      hnew = (1.f - z) * n + z * hold;
      __hip_atomic_store(&hex[((size_t)(s & 1) * 8 + grp) * (512 * 8) + ug * 8 + b_l],
                         hnew, __ATOMIC_RELAXED, __HIP_MEMORY_SCOPE_SYSTEM);
    }
    // drain hex stores (vmcnt(0) per wave at barrier) before WG's release bump
    __syncthreads();
    if (s < Tn - 1 && tid == 0)
      __hip_atomic_fetch_add(cnt, 1u, __ATOMIC_RELAXED, __HIP_MEMORY_SCOPE_SYSTEM);
    // out store off the release path (drained by next step's barrier)
    if (kq < 4)
      out[(size_t)((g * 8 + b_l) * Tn + t) * 1024 + d * DHn + ug] = hnew;
  }
}

// ---------------- lh[b*T+t][c] = h . Wc[c][:1024] + bc[c] ----------------
__global__ __launch_bounds__(256) void lh_kernel(
    const float* __restrict__ out_h, const float* __restrict__ Wc,
    const float* __restrict__ bc, float* __restrict__ lh)
{
  const int tid = threadIdx.x;
  const int wave = tid >> 6, lane = tid & 63;
#pragma unroll 1
  for (int it = 0; it < 16; it++) {
    const int row = blockIdx.x * 64 + wave * 16 + it;
    const float* hp = out_h + (size_t)row * 1024 + lane * 4;
    float4 hv[4];
#pragma unroll
    for (int j = 0; j < 4; j++) hv[j] = *reinterpret_cast<const float4*>(hp + 256 * j);
    float acc[Cn];
#pragma unroll
    for (int c = 0; c < Cn; c++) {
      const float* wp = Wc + (size_t)c * 1049 + lane * 4;
      float a = 0.f;
#pragma unroll
      for (int j = 0; j < 4; j++) {
        float4 wv = *reinterpret_cast<const float4*>(wp + 256 * j);
        a = fmaf(hv[j].x, wv.x, a); a = fmaf(hv[j].y, wv.y, a);
        a = fmaf(hv[j].z, wv.z, a); a = fmaf(hv[j].w, wv.w, a);
      }
      acc[c] = a;
    }
#pragma unroll
    for (int off = 32; off; off >>= 1)
#pragma unroll
      for (int c = 0; c < Cn; c++) acc[c] += __shfl_xor(acc[c], off);
    if (lane < Cn) lh[(size_t)row * 12 + lane] = acc[lane] + bc[lane];
  }
}

// ---------------- chain: per-batch argmax feedback ----------------
__global__ __launch_bounds__(64) void chain_kernel(
    const float* __restrict__ lh, const float* __restrict__ etab,
    float* __restrict__ outc)
{
  __shared__ float et[90];
  const int tid = threadIdx.x;
  if (tid < 90) et[tid] = etab[tid];
  __syncthreads();
  if (tid >= Bn) return;
  const int b = tid;
  const float* base = lh + (size_t)b * Tn * 12;
  float4 A0 = *reinterpret_cast<const float4*>(base);
  float4 A1 = *reinterpret_cast<const float4*>(base + 4);
  float c8 = base[8];
  int prev = Cn;
  for (int t = 0; t < Tn; t++) {
    float4 N0 = {0,0,0,0}, N1 = {0,0,0,0}; float nc8 = 0.f;
    if (t < Tn - 1) {
      const float* nb = base + (size_t)(t + 1) * 12;
      N0 = *reinterpret_cast<const float4*>(nb);
      N1 = *reinterpret_cast<const float4*>(nb + 4);
      nc8 = nb[8];
    }
    float lg[Cn] = {A0.x, A0.y, A0.z, A0.w, A1.x, A1.y, A1.z, A1.w, c8};
    const float* ep = &et[prev * Cn];
#pragma unroll
    for (int c = 0; c < Cn; c++) lg[c] += ep[c];
    float mx = lg[0]; int idx = 0;
#pragma unroll
    for (int c = 1; c < Cn; c++) if (lg[c] > mx) { mx = lg[c]; idx = c; }
    float e[Cn]; float sum = 0.f;
#pragma unroll
    for (int c = 0; c < Cn; c++) { e[c] = expf(lg[c] - mx); sum += e[c]; }
    const float inv = 1.f / sum;
    float* op = outc + ((size_t)b * Tn + t) * Cn;
#pragma unroll
    for (int c = 0; c < Cn; c++) op[c] = e[c] * inv;
    prev = idx;
    A0 = N0; A1 = N1; c8 = nc8;
  }
}

extern "C" void kernel_launch(void* const* d_in, const int* in_sizes, int n_in,
                              void* d_out, int out_size, void* d_ws, size_t ws_size,
                              hipStream_t stream) {
  const float* X      = (const float*)d_in[0];
  const float* pad    = (const float*)d_in[1];
  const float* lemb   = (const float*)d_in[2];
  const float* Wih_f  = (const float*)d_in[3];
  const float* Whh_f  = (const float*)d_in[4];
  const float* bih_f  = (const float*)d_in[5];
  const float* bhh_f  = (const float*)d_in[6];
  const float* Wih_b  = (const float*)d_in[7];
  const float* Whh_b  = (const float*)d_in[8];
  const float* bih_b  = (const float*)d_in[9];
  const float* bhh_b  = (const float*)d_in[10];
  const float* Wc     = (const float*)d_in[11];
  const float* bc     = (const float*)d_in[12];
  float* out = (float*)d_out;

  char* ws = (char*)d_ws;
  float*    gi   = (float*)ws;                                          // 100,663,296
  float4*   Wp   = (float4*)(ws + 100663296);                           // 8,388,608
  unsigned* sync = (unsigned*)(ws + 109051904);                         // 1,024
  float*    hex  = (float*)(ws + 109052928);                            // 262,144
  unsigned short* Xh = (unsigned short*)(ws + 109315072);               // 12,681,216
  unsigned short* Xl = (unsigned short*)(ws + 121996288);               // 12,681,216
  unsigned short* Bh = (unsigned short*)(ws + 134677504);               // 14,155,776
  unsigned short* Bl = (unsigned short*)(ws + 148833280);               // 14,155,776 -> 162,989,056
  float*    lh   = (float*)ws;                                          // post-gru alias
  float*    etab = (float*)(ws + 524288);                               // post-gru alias

  const bool preconv = (ws_size >= (size_t)162989056ULL);

  prep_kernel<<<dim3(2048), dim3(256), 0, stream>>>(Whh_f, Whh_b, Wp, sync);
  if (preconv) {
    prep_x_kernel<<<dim3((32 * 258 * 96 + 255) / 256), dim3(256), 0, stream>>>(X, pad, Xh, Xl);
    prep_wih_kernel<<<dim3((3072 * 288 + 255) / 256), dim3(256), 0, stream>>>(Wih_f, Wih_b, Bh, Bl);
    gi_gemm_pc_kernel<<<dim3(NCOL / GBN, MROW / GBM), dim3(256), 0, stream>>>(
        Xh, Xl, Bh, Bl, bih_f, bih_b, gi);
  } else {
    gi_gemm_mfma_kernel<<<dim3(NCOL / GBN, MROW / GBM), dim3(256), 0, stream>>>(
        X, pad, Wih_f, Wih_b, bih_f, bih_b, gi);
  }
  gru_rec5_kernel<<<dim3(256), dim3(512), 0, stream>>>(gi, Wp, bhh_f, bhh_b, sync, hex, out);
  etab_kernel<<<dim3(1), dim3(128), 0, stream>>>(lemb, Wc, etab);
  lh_kernel<<<dim3(128), dim3(256), 0, stream>>>(out, Wc, bc, lh);
  chain_kernel<<<dim3(1), dim3(64), 0, stream>>>(lh, etab, out + (size_t)MROW * 1024);
}

// Round 11
// 1722.398 us; speedup vs baseline: 2.0271x; 1.0049x over previous
//
#include <hip/hip_runtime.h>
#include <hip/hip_bf16.h>
#include <math.h>

#define Bn   32
#define Tn   256
#define DIN  768
#define DHn  512
#define DEn  25
#define Cn   9
#define K3   2304   // 3*DIN
#define H3   1536   // 3*DH
#define NCOL 3072   // 2*H3
#define MROW 8192   // B*T

typedef __attribute__((ext_vector_type(8))) short short8v;
typedef __attribute__((ext_vector_type(4))) float f32x4;

__device__ __forceinline__ unsigned short f2bf(float v) {
  __hip_bfloat16 h = __float2bfloat16(v);
  return __builtin_bit_cast(unsigned short, h);
}
__device__ __forceinline__ float bf2f(unsigned short u) {
  return __bfloat162float(__builtin_bit_cast(__hip_bfloat16, u));
}

// ================= merged prep: Wp + sync zero (+ Xh/Xl + Bh/Bl when preconv) ===========
// range [0, 524288): Wp float4 {r,z,n,0}  (also idx<8 zeroes sync)
// range [524288, 1316864): X/pad RNE hi-lo split -> Xh/Xl
// range [1316864, 2201600): Wih rows RNE hi-lo split -> Bh/Bl
__global__ __launch_bounds__(256) void prep_all_kernel(
    const float* __restrict__ Whh_f, const float* __restrict__ Whh_b,
    const float* __restrict__ X, const float* __restrict__ pad,
    const float* __restrict__ Wf, const float* __restrict__ Wb,
    float4* __restrict__ Wp, unsigned* __restrict__ sync,
    unsigned short* __restrict__ Xh, unsigned short* __restrict__ Xl,
    unsigned short* __restrict__ Bh, unsigned short* __restrict__ Bl,
    int total)
{
  int idx = blockIdx.x * 256 + threadIdx.x;
  if (idx >= total) return;
  if (idx < 8) sync[idx * 32] = 0u;

  if (idx < 524288) {
    // ---- Wp[d][slc(32)][u(16)][k(512)] float4 {r,z,n,0} (identical to prep_kernel) ----
    int f = idx;
    int k   = f & 511;
    int u   = (f >> 9) & 15;
    int slc = (f >> 13) & 31;
    int d   = f >> 18;
    const float* Wsrc = d ? Whh_b : Whh_f;
    int ug = slc * 16 + u;
    float4 v;
    v.x = Wsrc[(size_t)(0 * DHn + ug) * DHn + k];
    v.y = Wsrc[(size_t)(1 * DHn + ug) * DHn + k];
    v.z = Wsrc[(size_t)(2 * DHn + ug) * DHn + k];
    v.w = 0.f;
    Wp[f] = v;
  } else if (idx < 524288 + 792576) {
    // ---- X_pad hi/lo split (identical to prep_x_kernel) ----
    int e = idx - 524288;                        // 0 .. 32*258*96-1
    int k8 = e % 96;
    int row = e / 96;                            // b*258 + p
    int p = row % 258, b = row / 258;
    int off = k8 * 8;
    const float* src = (p == 0 || p == 257) ? (pad + off)
                                            : (X + (size_t)(b * Tn + (p - 1)) * DIN + off);
    float4 v0 = *reinterpret_cast<const float4*>(src);
    float4 v1 = *reinterpret_cast<const float4*>(src + 4);
    float av[8] = {v0.x, v0.y, v0.z, v0.w, v1.x, v1.y, v1.z, v1.w};
    short8v h8, l8;
#pragma unroll
    for (int q = 0; q < 8; q++) {
      unsigned short h = f2bf(av[q]);
      h8[q] = (short)h;
      l8[q] = (short)f2bf(av[q] - bf2f(h));
    }
    *reinterpret_cast<short8v*>(Xh + (size_t)row * DIN + off) = h8;
    *reinterpret_cast<short8v*>(Xl + (size_t)row * DIN + off) = l8;
  } else {
    // ---- Wih hi/lo split (identical to prep_wih_kernel) ----
    int e = idx - (524288 + 792576);             // 0 .. 3072*288-1
    int k8 = e % 288;
    int rr = e / 288;
    int off = k8 * 8;
    const float* src = (rr < H3) ? (Wf + (size_t)rr * K3 + off)
                                 : (Wb + (size_t)(rr - H3) * K3 + off);
    float4 v0 = *reinterpret_cast<const float4*>(src);
    float4 v1 = *reinterpret_cast<const float4*>(src + 4);
    float av[8] = {v0.x, v0.y, v0.z, v0.w, v1.x, v1.y, v1.z, v1.w};
    short8v h8, l8;
#pragma unroll
    for (int q = 0; q < 8; q++) {
      unsigned short h = f2bf(av[q]);
      h8[q] = (short)h;
      l8[q] = (short)f2bf(av[q] - bf2f(h));
    }
    *reinterpret_cast<short8v*>(Bh + (size_t)rr * K3 + off) = h8;
    *reinterpret_cast<short8v*>(Bl + (size_t)rr * K3 + off) = l8;
  }
}

// ================= gi pre-GEMM (preconverted bf16 operands) =================
#define GBM 128
#define GBN 128
#define GBK 64
#define ASTR 72   // shorts per LDS row (64 + 8 pad)

__global__ __launch_bounds__(256) void gi_gemm_pc_kernel(
    const unsigned short* __restrict__ Xh, const unsigned short* __restrict__ Xl,
    const unsigned short* __restrict__ Bh, const unsigned short* __restrict__ Bl,
    const float* __restrict__ bf, const float* __restrict__ bb,
    float* __restrict__ gi)
{
  __shared__ __align__(16) unsigned short LAh[GBM * ASTR];
  __shared__ __align__(16) unsigned short LAl[GBM * ASTR];
  __shared__ __align__(16) unsigned short LBh[GBN * ASTR];
  __shared__ __align__(16) unsigned short LBl[GBN * ASTR];

  const int bnb = blockIdx.x, bmb = blockIdx.y;
  const int tid = threadIdx.x;
  const int m0 = bmb * GBM, n0 = bnb * GBN;
  const bool isF = (n0 < H3);
  const float* bias = isF ? bf : bb;
  const int nb0 = isF ? n0 : (n0 - H3);

  const int r = tid >> 1, half = tid & 1;
  const int m = m0 + r;
  const int ab = m >> 8, tpos = m & 255;

  const int wave = tid >> 6, lane = tid & 63;
  const int wr = wave >> 1, wc = wave & 1;
  const int lrow = lane & 15, lk = (lane >> 4) * 8;

  f32x4 acc[4][4];
#pragma unroll
  for (int i = 0; i < 4; i++)
#pragma unroll
    for (int j = 0; j < 4; j++) acc[i][j] = (f32x4){0.f, 0.f, 0.f, 0.f};

  for (int k0 = 0; k0 < K3; k0 += GBK) {
#pragma unroll
    for (int j2 = 0; j2 < 4; j2++) {
      const int kg = k0 + half * 32 + j2 * 8;
      const int seg = (kg >= DIN) + (kg >= 2 * DIN);
      const int off = kg - seg * DIN;
      const int p = tpos + seg;
      const size_t xi = (size_t)(ab * 258 + p) * DIN + off;
      const size_t bi = (size_t)(n0 + r) * K3 + kg;
      short8v a_h = *reinterpret_cast<const short8v*>(Xh + xi);
      short8v a_l = *reinterpret_cast<const short8v*>(Xl + xi);
      short8v b_h = *reinterpret_cast<const short8v*>(Bh + bi);
      short8v b_l = *reinterpret_cast<const short8v*>(Bl + bi);
      const int si = r * ASTR + half * 32 + j2 * 8;
      *reinterpret_cast<short8v*>(&LAh[si]) = a_h;
      *reinterpret_cast<short8v*>(&LAl[si]) = a_l;
      *reinterpret_cast<short8v*>(&LBh[si]) = b_h;
      *reinterpret_cast<short8v*>(&LBl[si]) = b_l;
    }
    __syncthreads();

#pragma unroll
    for (int ksub = 0; ksub < 2; ksub++) {
      short8v fah[4], fal[4], fbh[4], fbl[4];
#pragma unroll
      for (int i = 0; i < 4; i++) {
        const int ai = (wr * 64 + i * 16 + lrow) * ASTR + ksub * 32 + lk;
        const int bi2 = (wc * 64 + i * 16 + lrow) * ASTR + ksub * 32 + lk;
        fah[i] = *reinterpret_cast<const short8v*>(&LAh[ai]);
        fal[i] = *reinterpret_cast<const short8v*>(&LAl[ai]);
        fbh[i] = *reinterpret_cast<const short8v*>(&LBh[bi2]);
        fbl[i] = *reinterpret_cast<const short8v*>(&LBl[bi2]);
      }
#pragma unroll
      for (int mi = 0; mi < 4; mi++)
#pragma unroll
        for (int ni = 0; ni < 4; ni++) {
          acc[mi][ni] = __builtin_amdgcn_mfma_f32_16x16x32_bf16(fah[mi], fbh[ni], acc[mi][ni], 0, 0, 0);
          acc[mi][ni] = __builtin_amdgcn_mfma_f32_16x16x32_bf16(fah[mi], fbl[ni], acc[mi][ni], 0, 0, 0);
          acc[mi][ni] = __builtin_amdgcn_mfma_f32_16x16x32_bf16(fal[mi], fbh[ni], acc[mi][ni], 0, 0, 0);
        }
    }
    __syncthreads();
  }

#pragma unroll
  for (int ni = 0; ni < 4; ni++) {
    const int nl = wc * 64 + ni * 16 + (lane & 15);
    const float bvv = bias[nb0 + nl];
#pragma unroll
    for (int mi = 0; mi < 4; mi++) {
      const int mg = m0 + wr * 64 + mi * 16 + (lane >> 4) * 4;
#pragma unroll
      for (int reg = 0; reg < 4; reg++)
        gi[(size_t)(mg + reg) * NCOL + n0 + nl] = acc[mi][ni][reg] + bvv;
    }
  }
}

// ================= fallback gemm (in-kernel split; identical math) =================
__global__ __launch_bounds__(256) void gi_gemm_mfma_kernel(
    const float* __restrict__ X, const float* __restrict__ pad,
    const float* __restrict__ Wf, const float* __restrict__ Wb,
    const float* __restrict__ bf, const float* __restrict__ bb,
    float* __restrict__ gi)
{
  __shared__ __align__(16) unsigned short Ah[GBM * ASTR];
  __shared__ __align__(16) unsigned short Al[GBM * ASTR];
  __shared__ __align__(16) unsigned short Bh2[GBN * ASTR];
  __shared__ __align__(16) unsigned short Bl2[GBN * ASTR];

  const int bnb = blockIdx.x, bmb = blockIdx.y;
  const int tid = threadIdx.x;
  const int m0 = bmb * GBM, n0 = bnb * GBN;
  const bool isF = (n0 < H3);
  const float* Wmat = isF ? Wf : Wb;
  const float* bias = isF ? bf : bb;
  const int nb0 = isF ? n0 : (n0 - H3);

  const int r = tid >> 1, half = tid & 1;
  const int m = m0 + r;
  const int ab = m >> 8, tpos = m & 255;
  const float* wrowp = Wmat + (size_t)(nb0 + r) * K3;

  const int wave = tid >> 6, lane = tid & 63;
  const int wr = wave >> 1, wc = wave & 1;
  const int lrow = lane & 15, lk = (lane >> 4) * 8;

  f32x4 acc[4][4];
#pragma unroll
  for (int i = 0; i < 4; i++)
#pragma unroll
    for (int j = 0; j < 4; j++) acc[i][j] = (f32x4){0.f, 0.f, 0.f, 0.f};

  for (int k0 = 0; k0 < K3; k0 += GBK) {
#pragma unroll
    for (int j2 = 0; j2 < 4; j2++) {
      const int kg = k0 + half * 32 + j2 * 8;
      const int seg = (kg >= DIN) + (kg >= 2 * DIN);
      const int off = kg - seg * DIN;
      const int p = tpos + seg;
      const float* srcA = (p == 0 || p == Tn + 1)
                            ? (pad + off)
                            : (X + (size_t)(ab * Tn + (p - 1)) * DIN + off);
      float4 a0 = *reinterpret_cast<const float4*>(srcA);
      float4 a1 = *reinterpret_cast<const float4*>(srcA + 4);
      const float* srcB = wrowp + kg;
      float4 b0 = *reinterpret_cast<const float4*>(srcB);
      float4 b1 = *reinterpret_cast<const float4*>(srcB + 4);
      float av[8] = {a0.x, a0.y, a0.z, a0.w, a1.x, a1.y, a1.z, a1.w};
      float bv[8] = {b0.x, b0.y, b0.z, b0.w, b1.x, b1.y, b1.z, b1.w};
      short8v ah8, al8, bh8, bl8;
#pragma unroll
      for (int q = 0; q < 8; q++) {
        unsigned short h = f2bf(av[q]);
        ah8[q] = (short)h;
        al8[q] = (short)f2bf(av[q] - bf2f(h));
        unsigned short g = f2bf(bv[q]);
        bh8[q] = (short)g;
        bl8[q] = (short)f2bf(bv[q] - bf2f(g));
      }
      const int si = r * ASTR + half * 32 + j2 * 8;
      *reinterpret_cast<short8v*>(&Ah[si]) = ah8;
      *reinterpret_cast<short8v*>(&Al[si]) = al8;
      *reinterpret_cast<short8v*>(&Bh2[si]) = bh8;
      *reinterpret_cast<short8v*>(&Bl2[si]) = bl8;
    }
    __syncthreads();
#pragma unroll
    for (int ksub = 0; ksub < 2; ksub++) {
      short8v fah[4], fal[4], fbh[4], fbl[4];
#pragma unroll
      for (int i = 0; i < 4; i++) {
        const int ai = (wr * 64 + i * 16 + lrow) * ASTR + ksub * 32 + lk;
        const int bi = (wc * 64 + i * 16 + lrow) * ASTR + ksub * 32 + lk;
        fah[i] = *reinterpret_cast<const short8v*>(&Ah[ai]);
        fal[i] = *reinterpret_cast<const short8v*>(&Al[ai]);
        fbh[i] = *reinterpret_cast<const short8v*>(&Bh2[bi]);
        fbl[i] = *reinterpret_cast<const short8v*>(&Bl2[bi]);
      }
#pragma unroll
      for (int mi = 0; mi < 4; mi++)
#pragma unroll
        for (int ni = 0; ni < 4; ni++) {
          acc[mi][ni] = __builtin_amdgcn_mfma_f32_16x16x32_bf16(fah[mi], fbh[ni], acc[mi][ni], 0, 0, 0);
          acc[mi][ni] = __builtin_amdgcn_mfma_f32_16x16x32_bf16(fah[mi], fbl[ni], acc[mi][ni], 0, 0, 0);
          acc[mi][ni] = __builtin_amdgcn_mfma_f32_16x16x32_bf16(fal[mi], fbh[ni], acc[mi][ni], 0, 0, 0);
        }
    }
    __syncthreads();
  }
#pragma unroll
  for (int ni = 0; ni < 4; ni++) {
    const int nl = wc * 64 + ni * 16 + (lane & 15);
    const float bvv = bias[nb0 + nl];
#pragma unroll
    for (int mi = 0; mi < 4; mi++) {
      const int mg = m0 + wr * 64 + mi * 16 + (lane >> 4) * 4;
#pragma unroll
      for (int reg = 0; reg < 4; reg++)
        gi[(size_t)(mg + reg) * NCOL + n0 + nl] = acc[mi][ni][reg] + bvv;
    }
  }
}

// ================= GRU recurrence (rec5: proven R7/R9 structure, untouched) =================
#define HSTRIDE 12

__global__ __launch_bounds__(512) void gru_rec5_kernel(
    const float* __restrict__ gi,
    const float4* __restrict__ Wp,
    const float* __restrict__ bhh_f, const float* __restrict__ bhh_b,
    unsigned* __restrict__ sync,
    float* __restrict__ hex,
    float* __restrict__ out)
{
  __shared__ __align__(16) float4 Wl[16 * 512];
  __shared__ __align__(16) float hl[512 * HSTRIDE];

  const int bid = blockIdx.x;
  const int xcd = bid & 7;
  const int d = xcd >> 2, g = xcd & 3;
  const int sl = bid >> 3;
  const int tid = threadIdx.x;
  const int ut = tid >> 5;
  const int kq2 = tid & 31;
  const int kq = kq2 & 15, bh = kq2 >> 4;
  const int grp = d * 4 + g;

  {
    const float4* src = Wp + (size_t)(d * 32 + sl) * 8192;
    for (int i = tid; i < 8192; i += 512) Wl[i] = src[i];
  }
  for (int i = tid; i < 512 * HSTRIDE; i += 512) hl[i] = 0.f;

  const float* bhh = d ? bhh_b : bhh_f;
  const int ug = sl * 16 + ut;
  const float br = bhh[ug], bz = bhh[DHn + ug], bn2 = bhh[2 * DHn + ug];
  const int blocal = ((kq & 1) << 1) | ((kq >> 1) & 1);
  const int b_l = bh * 4 + blocal;

  unsigned* cnt = sync + grp * 32;

  __syncthreads();

  for (int s = 0; s < Tn; s++) {
    const int t = d ? (Tn - 1 - s) : s;

    float ir = 0.f, iz = 0.f, inn = 0.f;
    if (kq < 4) {
      const int bg = g * 8 + b_l;
      const float* gp = gi + (size_t)(bg * Tn + t) * NCOL + d * H3 + ug;
      ir = gp[0]; iz = gp[DHn]; inn = gp[2 * DHn];
    }

    if (s > 0) {
      if (tid == 0) {
        const unsigned tgt = 32u * (unsigned)s;
        while (__hip_atomic_load(cnt, __ATOMIC_RELAXED, __HIP_MEMORY_SCOPE_SYSTEM) < tgt)
          __builtin_amdgcn_s_sleep(1);
      }
      __syncthreads();
      asm volatile("" ::: "memory");
      const uint64_t* src = reinterpret_cast<const uint64_t*>(
          hex + (size_t)(((s - 1) & 1) * 8 + grp) * (512 * 8));
#pragma unroll
      for (int j = 0; j < 4; j++) {
        int idx = tid + 512 * j;
        uint64_t v = __hip_atomic_load(src + idx,
                                       __ATOMIC_RELAXED, __HIP_MEMORY_SCOPE_SYSTEM);
        int fd = 2 * idx;
        int u = fd >> 3, b = fd & 7;
        *reinterpret_cast<uint64_t*>(&hl[u * HSTRIDE + b]) = v;
      }
      __syncthreads();
    }

    float acc[3][4];
#pragma unroll
    for (int gg = 0; gg < 3; gg++)
#pragma unroll
      for (int bb = 0; bb < 4; bb++) acc[gg][bb] = 0.f;

#pragma unroll 4
    for (int i = 0; i < 32; i++) {
      int k = i * 16 + kq;
      float4 wv = Wl[ut * 512 + k];
      float4 ha = *reinterpret_cast<const float4*>(&hl[k * HSTRIDE + bh * 4]);
      acc[0][0] = fmaf(wv.x, ha.x, acc[0][0]); acc[0][1] = fmaf(wv.x, ha.y, acc[0][1]);
      acc[0][2] = fmaf(wv.x, ha.z, acc[0][2]); acc[0][3] = fmaf(wv.x, ha.w, acc[0][3]);
      acc[1][0] = fmaf(wv.y, ha.x, acc[1][0]); acc[1][1] = fmaf(wv.y, ha.y, acc[1][1]);
      acc[1][2] = fmaf(wv.y, ha.z, acc[1][2]); acc[1][3] = fmaf(wv.y, ha.w, acc[1][3]);
      acc[2][0] = fmaf(wv.z, ha.x, acc[2][0]); acc[2][1] = fmaf(wv.z, ha.y, acc[2][1]);
      acc[2][2] = fmaf(wv.z, ha.z, acc[2][2]); acc[2][3] = fmaf(wv.z, ha.w, acc[2][3]);
    }

#pragma unroll
    for (int gg = 0; gg < 3; gg++)
#pragma unroll
      for (int bb = 0; bb < 4; bb++)
        acc[gg][bb] += __shfl_xor(acc[gg][bb], 8);

    float a2[3][2];
#pragma unroll
    for (int gg = 0; gg < 3; gg++)
#pragma unroll
      for (int j = 0; j < 2; j++) {
        float keep = (kq & 1) ? acc[gg][2 + j] : acc[gg][j];
        float send = (kq & 1) ? acc[gg][j] : acc[gg][2 + j];
        a2[gg][j] = keep + __shfl_xor(send, 1);
      }
    float a1[3];
#pragma unroll
    for (int gg = 0; gg < 3; gg++) {
      float keep = (kq & 2) ? a2[gg][1] : a2[gg][0];
      float send = (kq & 2) ? a2[gg][0] : a2[gg][1];
      a1[gg] = keep + __shfl_xor(send, 2);
    }
#pragma unroll
    for (int gg = 0; gg < 3; gg++)
      a1[gg] += __shfl_xor(a1[gg], 4);

    float hnew = 0.f;
    if (kq < 4) {
      const float r = 1.f / (1.f + expf(-(ir + a1[0] + br)));
      const float z = 1.f / (1.f + expf(-(iz + a1[1] + bz)));
      const float n = tanhf(inn + r * (a1[2] + bn2));
      const float hold = hl[ug * HSTRIDE + b_l];
      hnew = (1.f - z) * n + z * hold;
      __hip_atomic_store(&hex[((size_t)(s & 1) * 8 + grp) * (512 * 8) + ug * 8 + b_l],
                         hnew, __ATOMIC_RELAXED, __HIP_MEMORY_SCOPE_SYSTEM);
    }
    __syncthreads();
    if (s < Tn - 1 && tid == 0)
      __hip_atomic_fetch_add(cnt, 1u, __ATOMIC_RELAXED, __HIP_MEMORY_SCOPE_SYSTEM);
    if (kq < 4)
      out[(size_t)((g * 8 + b_l) * Tn + t) * 1024 + d * DHn + ug] = hnew;
  }
}

// ---------------- lh[b*T+t][c] = h . Wc[c][:1024] + bc[c] ----------------
__global__ __launch_bounds__(256) void lh_kernel(
    const float* __restrict__ out_h, const float* __restrict__ Wc,
    const float* __restrict__ bc, float* __restrict__ lh)
{
  const int tid = threadIdx.x;
  const int wave = tid >> 6, lane = tid & 63;
#pragma unroll 1
  for (int it = 0; it < 16; it++) {
    const int row = blockIdx.x * 64 + wave * 16 + it;
    const float* hp = out_h + (size_t)row * 1024 + lane * 4;
    float4 hv[4];
#pragma unroll
    for (int j = 0; j < 4; j++) hv[j] = *reinterpret_cast<const float4*>(hp + 256 * j);
    float acc[Cn];
#pragma unroll
    for (int c = 0; c < Cn; c++) {
      const float* wp = Wc + (size_t)c * 1049 + lane * 4;
      float a = 0.f;
#pragma unroll
      for (int j = 0; j < 4; j++) {
        float4 wv = *reinterpret_cast<const float4*>(wp + 256 * j);
        a = fmaf(hv[j].x, wv.x, a); a = fmaf(hv[j].y, wv.y, a);
        a = fmaf(hv[j].z, wv.z, a); a = fmaf(hv[j].w, wv.w, a);
      }
      acc[c] = a;
    }
#pragma unroll
    for (int off = 32; off; off >>= 1)
#pragma unroll
      for (int c = 0; c < Cn; c++) acc[c] += __shfl_xor(acc[c], off);
    if (lane < Cn) lh[(size_t)row * 12 + lane] = acc[lane] + bc[lane];
  }
}

// ---------------- chain: etab inline (bit-identical FMA loop) + argmax feedback ----------------
__global__ __launch_bounds__(64) void chain_kernel(
    const float* __restrict__ lh,
    const float* __restrict__ label_emb, const float* __restrict__ Wc,
    float* __restrict__ outc)
{
  __shared__ float et[90];
  const int tid = threadIdx.x;
  for (int e = tid; e < 90; e += 64) {
    int p = e / Cn, c = e % Cn;
    float a = 0.f;
#pragma unroll
    for (int j = 0; j < DEn; j++)
      a = fmaf(label_emb[p * DEn + j], Wc[(size_t)c * 1049 + 1024 + j], a);
    et[e] = a;
  }
  __syncthreads();
  if (tid >= Bn) return;
  const int b = tid;
  const float* base = lh + (size_t)b * Tn * 12;
  float4 A0 = *reinterpret_cast<const float4*>(base);
  float4 A1 = *reinterpret_cast<const float4*>(base + 4);
  float c8 = base[8];
  int prev = Cn;
  for (int t = 0; t < Tn; t++) {
    float4 N0 = {0,0,0,0}, N1 = {0,0,0,0}; float nc8 = 0.f;
    if (t < Tn - 1) {
      const float* nb = base + (size_t)(t + 1) * 12;
      N0 = *reinterpret_cast<const float4*>(nb);
      N1 = *reinterpret_cast<const float4*>(nb + 4);
      nc8 = nb[8];
    }
    float lg[Cn] = {A0.x, A0.y, A0.z, A0.w, A1.x, A1.y, A1.z, A1.w, c8};
    const float* ep = &et[prev * Cn];
#pragma unroll
    for (int c = 0; c < Cn; c++) lg[c] += ep[c];
    float mx = lg[0]; int idx = 0;
#pragma unroll
    for (int c = 1; c < Cn; c++) if (lg[c] > mx) { mx = lg[c]; idx = c; }
    float e[Cn]; float sum = 0.f;
#pragma unroll
    for (int c = 0; c < Cn; c++) { e[c] = expf(lg[c] - mx); sum += e[c]; }
    const float inv = 1.f / sum;
    float* op = outc + ((size_t)b * Tn + t) * Cn;
#pragma unroll
    for (int c = 0; c < Cn; c++) op[c] = e[c] * inv;
    prev = idx;
    A0 = N0; A1 = N1; c8 = nc8;
  }
}

extern "C" void kernel_launch(void* const* d_in, const int* in_sizes, int n_in,
                              void* d_out, int out_size, void* d_ws, size_t ws_size,
                              hipStream_t stream) {
  const float* X      = (const float*)d_in[0];
  const float* pad    = (const float*)d_in[1];
  const float* lemb   = (const float*)d_in[2];
  const float* Wih_f  = (const float*)d_in[3];
  const float* Whh_f  = (const float*)d_in[4];
  const float* bih_f  = (const float*)d_in[5];
  const float* bhh_f  = (const float*)d_in[6];
  const float* Wih_b  = (const float*)d_in[7];
  const float* Whh_b  = (const float*)d_in[8];
  const float* bih_b  = (const float*)d_in[9];
  const float* bhh_b  = (const float*)d_in[10];
  const float* Wc     = (const float*)d_in[11];
  const float* bc     = (const float*)d_in[12];
  float* out = (float*)d_out;

  char* ws = (char*)d_ws;
  float*    gi   = (float*)ws;                                          // 100,663,296
  float4*   Wp   = (float4*)(ws + 100663296);                           // 8,388,608
  unsigned* sync = (unsigned*)(ws + 109051904);                         // 1,024
  float*    hex  = (float*)(ws + 109052928);                            // 262,144
  unsigned short* Xh = (unsigned short*)(ws + 109315072);               // 12,681,216
  unsigned short* Xl = (unsigned short*)(ws + 121996288);               // 12,681,216
  unsigned short* Bh = (unsigned short*)(ws + 134677504);               // 14,155,776
  unsigned short* Bl = (unsigned short*)(ws + 148833280);               // 14,155,776 -> 162,989,056
  float*    lh   = (float*)ws;                                          // post-gru alias (gi dead)

  const bool preconv = (ws_size >= (size_t)162989056ULL);
  const int prep_total = preconv ? (524288 + 792576 + 884736) : 524288;

  prep_all_kernel<<<dim3((prep_total + 255) / 256), dim3(256), 0, stream>>>(
      Whh_f, Whh_b, X, pad, Wih_f, Wih_b, Wp, sync, Xh, Xl, Bh, Bl, prep_total);
  if (preconv) {
    gi_gemm_pc_kernel<<<dim3(NCOL / GBN, MROW / GBM), dim3(256), 0, stream>>>(
        Xh, Xl, Bh, Bl, bih_f, bih_b, gi);
  } else {
    gi_gemm_mfma_kernel<<<dim3(NCOL / GBN, MROW / GBM), dim3(256), 0, stream>>>(
        X, pad, Wih_f, Wih_b, bih_f, bih_b, gi);
  }
  gru_rec5_kernel<<<dim3(256), dim3(512), 0, stream>>>(gi, Wp, bhh_f, bhh_b, sync, hex, out);
  lh_kernel<<<dim3(128), dim3(256), 0, stream>>>(out, Wc, bc, lh);
  chain_kernel<<<dim3(1), dim3(64), 0, stream>>>(lh, lemb, Wc, out + (size_t)MROW * 1024);
}